// Round 1
// baseline (416.853 us; speedup 1.0000x reference)
//
#include <hip/hip_runtime.h>
#include <hip/hip_cooperative_groups.h>

// T=4096, B=8, E=512. Dual EMA (pos/neg split) along T. fp32 in/out.
//   pb = sigmoid(raw_pos_beta[e]); nb = sigmoid(raw_neg_beta[e])
//   mem_p[t] = pb*mem_p[t-1] + max(x,0)*(1-pb)
//   mem_n[t] = nb*mem_n[t-1] + min(x,0)*(1-nb)
//   out[t,b,e] = mem_p + mem_n
//
// Fused single cooperative kernel (chunked scan, C=256 chunks of L=16):
//   Phase A: thread (c,b,e4) loads its 16 x-float4s into REGISTERS, computes
//            local finals with zero init, publishes them into d_out at
//            t=c*16+0 (pos) / t=c*16+1 (neg).
//   grid.sync()  (device-scope fences -> cross-XCD visible)
//   Phase B: 8192 threads (s,b,e) serially scan the 256 chunk finals,
//            replacing each with the carry INTO that chunk (beta^16 step).
//   grid.sync()
//   Phase C: each thread reads its 2 carry float4s, replays the local scan
//            FROM REGISTERS, overwrites the whole chunk of output.
// Traffic: read x once (64MB) + write out once (64MB) + ~24MB carry slots,
// vs 216MB for the previous 3-kernel version. Registers: 64 VGPR x-chunk +
// ~45 others; __launch_bounds__(256,4) keeps <=128 VGPR so 4 blocks/CU
// co-reside (1024 blocks total = full grid resident, cooperative-legal).
// Fallback: previous verified 3-kernel path if cooperative launch is
// rejected (e.g. unsupported under graph capture on this stack).

#define T_DIM 4096
#define B_DIM 8
#define E_DIM 512
#define CHUNK_L 16
#define NCHUNK (T_DIM / CHUNK_L)   // 256
#define BE (B_DIM * E_DIM)         // 4096 elements per t-step

namespace cg = cooperative_groups;

__device__ __forceinline__ float sigmoidf_(float x) { return 1.0f / (1.0f + __expf(-x)); }

__global__ __launch_bounds__(256, 4) void ParallelDLIEMA_17789754541002_kernel(
        const float* __restrict__ x,
        const float* __restrict__ rp,
        const float* __restrict__ rn,
        float* __restrict__ out) {
    const int gtid = blockIdx.x * 256 + threadIdx.x;
    const int e4 = gtid & 127;          // E/4 = 128
    const int b  = (gtid >> 7) & 7;
    const int c  = gtid >> 10;          // 0..255
    const int e  = e4 * 4;

    float4 rp4 = *(const float4*)(rp + e);
    float4 rn4 = *(const float4*)(rn + e);
    float bp[4] = {sigmoidf_(rp4.x), sigmoidf_(rp4.y), sigmoidf_(rp4.z), sigmoidf_(rp4.w)};
    float bn[4] = {sigmoidf_(rn4.x), sigmoidf_(rn4.y), sigmoidf_(rn4.z), sigmoidf_(rn4.w)};

    const int base = c * CHUNK_L * BE + b * E_DIM + e;

    // ---- Phase A: x -> registers once; local scan (zero init); publish finals.
    float4 xr[CHUNK_L];
    #pragma unroll
    for (int k = 0; k < CHUNK_L; k++)
        xr[k] = *(const float4*)(x + base + k * BE);

    {
        float fp[4] = {0.f, 0.f, 0.f, 0.f};
        float fn[4] = {0.f, 0.f, 0.f, 0.f};
        #pragma unroll
        for (int k = 0; k < CHUNK_L; k++) {
            float f[4] = {xr[k].x, xr[k].y, xr[k].z, xr[k].w};
            #pragma unroll
            for (int j = 0; j < 4; j++) {
                fp[j] = bp[j] * fp[j] + fmaxf(f[j], 0.f) * (1.0f - bp[j]);
                fn[j] = bn[j] * fn[j] + fminf(f[j], 0.f) * (1.0f - bn[j]);
            }
        }
        *(float4*)(out + base)      = make_float4(fp[0], fp[1], fp[2], fp[3]);
        *(float4*)(out + base + BE) = make_float4(fn[0], fn[1], fn[2], fn[3]);
    }

    cg::this_grid().sync();

    // ---- Phase B: serial carry scan across chunks (first 8192 threads).
    if (gtid < 2 * BE) {
        const int eb = gtid & 511;
        const int bb = (gtid >> 9) & 7;
        const int s  = gtid >> 12;                 // 0 = pos, 1 = neg
        float beta = sigmoidf_(s ? rn[eb] : rp[eb]);
        float bl = beta * beta; bl *= bl; bl *= bl; bl *= bl;  // beta^16
        float* p = out + s * BE + bb * E_DIM + eb;
        float carry = 0.f;
        for (int g = 0; g < NCHUNK / 16; g++) {
            float fv[16];
            #pragma unroll
            for (int u = 0; u < 16; u++) fv[u] = p[(g * 16 + u) * (CHUNK_L * BE)];
            #pragma unroll
            for (int u = 0; u < 16; u++) {
                p[(g * 16 + u) * (CHUNK_L * BE)] = carry;   // carry INTO chunk
                carry = bl * carry + fv[u];
            }
        }
    }

    cg::this_grid().sync();

    // ---- Phase C: seed from carries; replay local scan from registers.
    float4 cp = *(const float4*)(out + base);
    float4 cn = *(const float4*)(out + base + BE);
    float lp[4] = {cp.x, cp.y, cp.z, cp.w};
    float ln[4] = {cn.x, cn.y, cn.z, cn.w};
    #pragma unroll
    for (int k = 0; k < CHUNK_L; k++) {
        float f[4] = {xr[k].x, xr[k].y, xr[k].z, xr[k].w};
        float o[4];
        #pragma unroll
        for (int j = 0; j < 4; j++) {
            lp[j] = bp[j] * lp[j] + fmaxf(f[j], 0.f) * (1.0f - bp[j]);
            ln[j] = bn[j] * ln[j] + fminf(f[j], 0.f) * (1.0f - bn[j]);
            o[j] = lp[j] + ln[j];
        }
        *(float4*)(out + base + k * BE) = make_float4(o[0], o[1], o[2], o[3]);
    }
}

// ======================= fallback: previous verified 3-kernel path =======

__global__ __launch_bounds__(256) void k1_local(
        const float* __restrict__ x,
        const float* __restrict__ rp,
        const float* __restrict__ rn,
        float* __restrict__ out) {
    int gtid = blockIdx.x * 256 + threadIdx.x;
    int e4 = gtid & 127;
    int b  = (gtid >> 7) & 7;
    int c  = gtid >> 10;
    int e  = e4 * 4;

    float4 rp4 = *(const float4*)(rp + e);
    float4 rn4 = *(const float4*)(rn + e);
    float bp[4] = {sigmoidf_(rp4.x), sigmoidf_(rp4.y), sigmoidf_(rp4.z), sigmoidf_(rp4.w)};
    float bn[4] = {sigmoidf_(rn4.x), sigmoidf_(rn4.y), sigmoidf_(rn4.z), sigmoidf_(rn4.w)};

    float fp4[4] = {0.f, 0.f, 0.f, 0.f};
    float fn4[4] = {0.f, 0.f, 0.f, 0.f};
    int base = c * CHUNK_L * BE + b * E_DIM + e;
    #pragma unroll
    for (int k = 0; k < CHUNK_L; k++) {
        float4 xv = *(const float4*)(x + base + k * BE);
        float f[4] = {xv.x, xv.y, xv.z, xv.w};
        #pragma unroll
        for (int j = 0; j < 4; j++) {
            fp4[j] = bp[j] * fp4[j] + fmaxf(f[j], 0.f) * (1.0f - bp[j]);
            fn4[j] = bn[j] * fn4[j] + fminf(f[j], 0.f) * (1.0f - bn[j]);
        }
    }
    *(float4*)(out + base + 0 * BE) = make_float4(fp4[0], fp4[1], fp4[2], fp4[3]);
    *(float4*)(out + base + 1 * BE) = make_float4(fn4[0], fn4[1], fn4[2], fn4[3]);
}

__global__ __launch_bounds__(256) void k_carry(const float* __restrict__ rp,
                                               const float* __restrict__ rn,
                                               float* __restrict__ out) {
    int gtid = blockIdx.x * 256 + threadIdx.x;
    int e = gtid & 511;
    int b = (gtid >> 9) & 7;
    int s = gtid >> 12;
    float beta = sigmoidf_(s ? rn[e] : rp[e]);
    float bl = beta * beta; bl = bl * bl; bl = bl * bl; bl = bl * bl;

    float* p = out + s * BE + b * E_DIM + e;
    float carry = 0.f;
    for (int g = 0; g < NCHUNK / 16; g++) {
        float fv[16];
        #pragma unroll
        for (int u = 0; u < 16; u++) fv[u] = p[(g * 16 + u) * (CHUNK_L * BE)];
        #pragma unroll
        for (int u = 0; u < 16; u++) {
            p[(g * 16 + u) * (CHUNK_L * BE)] = carry;
            carry = bl * carry + fv[u];
        }
    }
}

__global__ __launch_bounds__(256) void k_out(const float* __restrict__ x,
                                             const float* __restrict__ rp,
                                             const float* __restrict__ rn,
                                             float* __restrict__ out) {
    int gtid = blockIdx.x * 256 + threadIdx.x;
    int e4 = gtid & 127;
    int b  = (gtid >> 7) & 7;
    int c  = gtid >> 10;
    int e  = e4 * 4;

    float4 rp4 = *(const float4*)(rp + e);
    float4 rn4 = *(const float4*)(rn + e);
    float bp[4] = {sigmoidf_(rp4.x), sigmoidf_(rp4.y), sigmoidf_(rp4.z), sigmoidf_(rp4.w)};
    float bn[4] = {sigmoidf_(rn4.x), sigmoidf_(rn4.y), sigmoidf_(rn4.z), sigmoidf_(rn4.w)};

    int base = c * CHUNK_L * BE + b * E_DIM + e;
    float4 cp = *(const float4*)(out + base + 0 * BE);
    float4 cn = *(const float4*)(out + base + 1 * BE);
    float lp[4] = {cp.x, cp.y, cp.z, cp.w};
    float ln[4] = {cn.x, cn.y, cn.z, cn.w};

    #pragma unroll
    for (int k = 0; k < CHUNK_L; k++) {
        float4 xv = *(const float4*)(x + base + k * BE);
        float f[4] = {xv.x, xv.y, xv.z, xv.w};
        float o[4];
        #pragma unroll
        for (int j = 0; j < 4; j++) {
            lp[j] = bp[j] * lp[j] + fmaxf(f[j], 0.f) * (1.0f - bp[j]);
            ln[j] = bn[j] * ln[j] + fminf(f[j], 0.f) * (1.0f - bn[j]);
            o[j] = lp[j] + ln[j];
        }
        *(float4*)(out + base + k * BE) = make_float4(o[0], o[1], o[2], o[3]);
    }
}

extern "C" void kernel_launch(void* const* d_in, const int* in_sizes, int n_in,
                              void* d_out, int out_size, void* d_ws, size_t ws_size,
                              hipStream_t stream) {
    const float* x  = (const float*)d_in[0];
    const float* rp = (const float*)d_in[1];
    const float* rn = (const float*)d_in[2];
    float* out = (float*)d_out;

    void* args[] = {(void*)&x, (void*)&rp, (void*)&rn, (void*)&out};
    hipError_t err = hipLaunchCooperativeKernel(
        (const void*)ParallelDLIEMA_17789754541002_kernel,
        dim3(1024), dim3(256), args, 0, stream);

    if (err != hipSuccess) {
        // Cooperative launch rejected (e.g. graph-capture or occupancy):
        // fall back to the verified 3-kernel chunked-scan path (135.9 us).
        k1_local<<<1024, 256, 0, stream>>>(x, rp, rn, out);
        k_carry<<<32, 256, 0, stream>>>(rp, rn, out);
        k_out<<<1024, 256, 0, stream>>>(x, rp, rn, out);
    }
}

// Round 3
// 150.791 us; speedup vs baseline: 2.7644x; 2.7644x over previous
//
#include <hip/hip_runtime.h>

// T=4096, B=8, E=512. Dual EMA (pos/neg split) along T. fp32 in/out.
//   pb = sigmoid(raw_pos_beta[e]); nb = sigmoid(raw_neg_beta[e])
//   mem_p[t] = pb*mem_p[t-1] + max(x,0)*(1-pb)
//   mem_n[t] = nb*mem_n[t-1] + min(x,0)*(1-nb)
//   out[t,b,e] = mem_p + mem_n
//
// Chunked scan, C=256 chunks of L=16 along T. 3 dispatches (cooperative
// grid.sync measured catastrophic in round 1: 2 syncs + forced spill of the
// register-held x chunk -> 321us; abandoned).
//   K1: per-(chunk,b,e) local finals with zero init -> fin[] (d_ws compact
//       layout if ws_size permits, else the verified in-out carry slots).
//   K2: WAVE-PARALLEL carry scan: one 64-lane wave per (state,b,e) column,
//       4 chunks/lane, affine-composition inclusive scan via __shfl_up
//       (carry' = beta^16*carry + f  ==  (A,B) composition). 2048 blocks
//       instead of 32 -> kills the 16 serial ~900-cycle rounds of the old
//       per-thread scan and the 12%-of-CUs underutilization.
//   K3: re-runs local scans seeded with carries, writes output with
//       NON-TEMPORAL stores (out never re-read; protects x's LLC residency
//       so K3's x re-read stays a 256MB-L3 hit instead of HBM).
// fin layout: fin[c*cs + s*BE + b*512 + e]; cs = 2*BE (ws mode) or 16*BE
// (fallback: finals live in out's t=c*16+{0,1} rows, verified in round 0).
// NOTE: __builtin_nontemporal_store needs a clang vector type, not HIP's
// float4 class -> use ext_vector_type(4) alias (same 16B layout).

#define T_DIM 4096
#define B_DIM 8
#define E_DIM 512
#define CHUNK_L 16
#define NCHUNK (T_DIM / CHUNK_L)   // 256
#define BE (B_DIM * E_DIM)         // 4096 elements per t-step

typedef float f4_t __attribute__((ext_vector_type(4)));

__device__ __forceinline__ float sigmoidf_(float x) { return 1.0f / (1.0f + __expf(-x)); }

// K1: 262144 threads; thread = (c, b, e4). 16 strided float4 loads of x.
__global__ __launch_bounds__(256) void ParallelDLIEMA_17789754541002_kernel(
        const float* __restrict__ x,
        const float* __restrict__ rp,
        const float* __restrict__ rn,
        float* __restrict__ fin, int cs) {
    int gtid = blockIdx.x * 256 + threadIdx.x;
    int e4 = gtid & 127;          // E/4 = 128
    int b  = (gtid >> 7) & 7;
    int c  = gtid >> 10;          // 0..255
    int e  = e4 * 4;

    float4 rp4 = *(const float4*)(rp + e);
    float4 rn4 = *(const float4*)(rn + e);
    float bp[4] = {sigmoidf_(rp4.x), sigmoidf_(rp4.y), sigmoidf_(rp4.z), sigmoidf_(rp4.w)};
    float bn[4] = {sigmoidf_(rn4.x), sigmoidf_(rn4.y), sigmoidf_(rn4.z), sigmoidf_(rn4.w)};

    float fp4[4] = {0.f, 0.f, 0.f, 0.f};
    float fn4[4] = {0.f, 0.f, 0.f, 0.f};
    int xbase = c * CHUNK_L * BE + b * E_DIM + e;
    #pragma unroll
    for (int k = 0; k < CHUNK_L; k++) {
        float4 xv = *(const float4*)(x + xbase + k * BE);
        float f[4] = {xv.x, xv.y, xv.z, xv.w};
        #pragma unroll
        for (int j = 0; j < 4; j++) {
            fp4[j] = bp[j] * fp4[j] + fmaxf(f[j], 0.f) * (1.0f - bp[j]);
            fn4[j] = bn[j] * fn4[j] + fminf(f[j], 0.f) * (1.0f - bn[j]);
        }
    }
    int fbase = c * cs + b * E_DIM + e;
    *(float4*)(fin + fbase)      = make_float4(fp4[0], fp4[1], fp4[2], fp4[3]);
    *(float4*)(fin + fbase + BE) = make_float4(fn4[0], fn4[1], fn4[2], fn4[3]);
}

// K2: wave-parallel carry scan. One wave per (s,b,e) column, 8192 waves,
// 2048 blocks. Per lane: 4 chunk-finals; inclusive affine scan across lanes.
__global__ __launch_bounds__(256) void k_carry_par(const float* __restrict__ rp,
                                                   const float* __restrict__ rn,
                                                   float* __restrict__ fin, int cs) {
    int col  = blockIdx.x * 4 + (threadIdx.x >> 6);  // 0..8191
    int lane = threadIdx.x & 63;
    int e = col & 511;
    int b = (col >> 9) & 7;
    int s = col >> 12;                               // 0 = pos, 1 = neg
    float beta = sigmoidf_(s ? rn[e] : rp[e]);
    float bL = beta * beta; bL *= bL; bL *= bL; bL *= bL;   // beta^16

    float* p = fin + s * BE + b * E_DIM + e;
    int c0 = lane * 4;
    float f0 = p[(c0 + 0) * cs];
    float f1 = p[(c0 + 1) * cs];
    float f2 = p[(c0 + 2) * cs];
    float f3 = p[(c0 + 3) * cs];

    // lane-local aggregate: carry_out = A*carry_in + B over 4 chunks
    float B = ((f0 * bL + f1) * bL + f2) * bL + f3;
    float bL2 = bL * bL;
    float A = bL2 * bL2;                              // beta^64

    // inclusive scan over lanes: composition (left-to-right)
    #pragma unroll
    for (int d = 1; d < 64; d <<= 1) {
        float Bu = __shfl_up(B, d);
        float Au = __shfl_up(A, d);
        if (lane >= d) { B = Bu * A + B; A = Au * A; }
    }
    float prev = __shfl_up(B, 1);
    float cin = (lane == 0) ? 0.f : prev;             // carry INTO chunk c0

    p[(c0 + 0) * cs] = cin;  float t0 = bL * cin + f0;
    p[(c0 + 1) * cs] = t0;   float t1 = bL * t0 + f1;
    p[(c0 + 2) * cs] = t1;   float t2 = bL * t1 + f2;
    p[(c0 + 3) * cs] = t2;
}

// K3: same shape as K1; seed from carries, write final output (nt stores).
__global__ __launch_bounds__(256) void k_out(const float* __restrict__ x,
                                             const float* __restrict__ rp,
                                             const float* __restrict__ rn,
                                             const float* __restrict__ fin, int cs,
                                             float* __restrict__ out) {
    int gtid = blockIdx.x * 256 + threadIdx.x;
    int e4 = gtid & 127;
    int b  = (gtid >> 7) & 7;
    int c  = gtid >> 10;
    int e  = e4 * 4;

    float4 rp4 = *(const float4*)(rp + e);
    float4 rn4 = *(const float4*)(rn + e);
    float bp[4] = {sigmoidf_(rp4.x), sigmoidf_(rp4.y), sigmoidf_(rp4.z), sigmoidf_(rp4.w)};
    float bn[4] = {sigmoidf_(rn4.x), sigmoidf_(rn4.y), sigmoidf_(rn4.z), sigmoidf_(rn4.w)};

    int fbase = c * cs + b * E_DIM + e;
    float4 cp = *(const float4*)(fin + fbase);
    float4 cn = *(const float4*)(fin + fbase + BE);
    float lp[4] = {cp.x, cp.y, cp.z, cp.w};
    float ln[4] = {cn.x, cn.y, cn.z, cn.w};

    int base = c * CHUNK_L * BE + b * E_DIM + e;
    #pragma unroll
    for (int k = 0; k < CHUNK_L; k++) {
        float4 xv = *(const float4*)(x + base + k * BE);
        float f[4] = {xv.x, xv.y, xv.z, xv.w};
        float o[4];
        #pragma unroll
        for (int j = 0; j < 4; j++) {
            lp[j] = bp[j] * lp[j] + fmaxf(f[j], 0.f) * (1.0f - bp[j]);
            ln[j] = bn[j] * ln[j] + fminf(f[j], 0.f) * (1.0f - bn[j]);
            o[j] = lp[j] + ln[j];
        }
        f4_t ov = {o[0], o[1], o[2], o[3]};
        __builtin_nontemporal_store(ov, (f4_t*)(out + base + k * BE));
    }
}

extern "C" void kernel_launch(void* const* d_in, const int* in_sizes, int n_in,
                              void* d_out, int out_size, void* d_ws, size_t ws_size,
                              hipStream_t stream) {
    const float* x  = (const float*)d_in[0];
    const float* rp = (const float*)d_in[1];
    const float* rn = (const float*)d_in[2];
    float* out = (float*)d_out;

    // finals buffer: compact in d_ws if it fits, else the verified in-out slots
    size_t need = (size_t)NCHUNK * 2 * BE * sizeof(float);   // 8 MB
    float* fin;
    int cs;
    if (ws_size >= need && d_ws != nullptr) {
        fin = (float*)d_ws;
        cs  = 2 * BE;             // compact [c][s][b][e]
    } else {
        fin = out;
        cs  = CHUNK_L * BE;       // finals live at t = c*16 + {0,1} rows of out
    }

    // K1: 256 chunks * 8 b * 128 e-quads = 262144 threads
    ParallelDLIEMA_17789754541002_kernel<<<1024, 256, 0, stream>>>(x, rp, rn, fin, cs);
    // K2: 8192 columns, one wave each -> 2048 blocks
    k_carry_par<<<2048, 256, 0, stream>>>(rp, rn, fin, cs);
    // K3: same shape as K1
    k_out<<<1024, 256, 0, stream>>>(x, rp, rn, fin, cs, out);
}